// Round 6
// baseline (141.673 us; speedup 1.0000x reference)
//
#include <hip/hip_runtime.h>
#include <hip/hip_bf16.h>

// Problem constants
#define D_IN 1024
#define D_EMB 512
#define HIDDEN 256
#define NUM_CLASSES 64
#define N_SUPPORT 4096
#define N_QUERY 8192

typedef __bf16 bf16x8 __attribute__((ext_vector_type(8)));
typedef float f32x4 __attribute__((ext_vector_type(4)));

// ---------------------------------------------------------------------------
// Fused transpose of both weight matrices -> bf16 [cols][rows]:
//   blocks [0,512):  W_e [1024][512]  -> WeT [512][1024]
//   blocks [512,640): W1[:512][256]   -> WqT [256][512]
// ---------------------------------------------------------------------------
__global__ void transpose_weights(const float* __restrict__ W_e,
                                  const float* __restrict__ W1,
                                  __bf16* __restrict__ WeT,
                                  __bf16* __restrict__ WqT) {
  __shared__ float tile[32][33];
  const float* in;
  __bf16* out;
  int bx, by, rows, cols;
  int b = blockIdx.x;
  if (b < 512) {
    in = W_e; out = WeT; rows = D_IN; cols = D_EMB;
    bx = (b & 15) * 32; by = (b >> 4) * 32;
  } else {
    b -= 512;
    in = W1; out = WqT; rows = D_EMB; cols = HIDDEN;  // W1[:512] only
    bx = (b & 7) * 32; by = (b >> 3) * 32;
  }
  int tx = threadIdx.x;
  int ty = threadIdx.y;
#pragma unroll
  for (int i = ty; i < 32; i += 8)
    tile[i][tx] = in[(long)(by + i) * cols + bx + tx];
  __syncthreads();
#pragma unroll
  for (int i = ty; i < 32; i += 8)
    out[(long)(bx + i) * rows + by + tx] = (__bf16)tile[tx][i];
}

// ---------------------------------------------------------------------------
// No-LDS MFMA GEMM: 1 wave per block, 64x64 output tile per wave.
//   C[64x64] = A[64xK] @ BT[64xK]^T (+bias, opt relu)
// All operands loaded global->register in the exact MFMA fragment layout
// (row = l&15, k = (l>>4)*8 + j). No LDS, no barriers, no bank conflicts;
// compiler tracks register deps and emits counted vmcnt itself.
// A_FP32: A is fp32 (support/query), cvt to bf16 in-register.
// OUT_BF16: relu(acc+bias) -> bf16; else acc+bias -> f32.
// ---------------------------------------------------------------------------
template <int K, bool A_FP32, bool OUT_BF16>
__global__ __launch_bounds__(64) void gemm_nolds(
    const float* __restrict__ Asup, const float* __restrict__ Aqry,
    const __bf16* __restrict__ Abf, const __bf16* __restrict__ BT,
    const float* __restrict__ bias, void* __restrict__ Cv, int Ncols) {
  const int lane = threadIdx.x;
  const int l16 = lane & 15;
  const int half = lane >> 4;  // 0..3
  const int m0 = blockIdx.x * 64;
  const int n0 = blockIdx.y * 64;

  const float* Af = nullptr;
  const __bf16* Ab = nullptr;
  if (A_FP32) {
    // 64-row blocks never straddle the support/query boundary (4096%64==0)
    Af = (m0 < N_SUPPORT) ? Asup + (long)m0 * K
                          : Aqry + (long)(m0 - N_SUPPORT) * K;
  } else {
    Ab = Abf + (long)m0 * K;
  }

  // per-lane row offsets (elements); fit in 32 bits
  int arow[4], brow[4];
#pragma unroll
  for (int m = 0; m < 4; ++m) arow[m] = (m * 16 + l16) * K;
#pragma unroll
  for (int n = 0; n < 4; ++n) brow[n] = (n0 + n * 16 + l16) * K;

  f32x4 acc[4][4];
#pragma unroll
  for (int m = 0; m < 4; ++m)
#pragma unroll
    for (int n = 0; n < 4; ++n) acc[m][n] = (f32x4)0.0f;

#pragma unroll 2
  for (int s = 0; s < K / 32; ++s) {
    const int kb = s * 32 + half * 8;
    bf16x8 a[4], b[4];
#pragma unroll
    for (int n = 0; n < 4; ++n)
      b[n] = *(const bf16x8*)(BT + brow[n] + kb);
    if (A_FP32) {
#pragma unroll
      for (int m = 0; m < 4; ++m) {
        f32x4 lo = *(const f32x4*)(Af + arow[m] + kb);
        f32x4 hi = *(const f32x4*)(Af + arow[m] + kb + 4);
        bf16x8 t;
        t[0] = (__bf16)lo[0]; t[1] = (__bf16)lo[1];
        t[2] = (__bf16)lo[2]; t[3] = (__bf16)lo[3];
        t[4] = (__bf16)hi[0]; t[5] = (__bf16)hi[1];
        t[6] = (__bf16)hi[2]; t[7] = (__bf16)hi[3];
        a[m] = t;
      }
    } else {
#pragma unroll
      for (int m = 0; m < 4; ++m)
        a[m] = *(const bf16x8*)(Ab + arow[m] + kb);
    }
#pragma unroll
    for (int m = 0; m < 4; ++m)
#pragma unroll
      for (int n = 0; n < 4; ++n)
        acc[m][n] = __builtin_amdgcn_mfma_f32_16x16x32_bf16(a[m], b[n],
                                                            acc[m][n], 0, 0, 0);
  }

  // epilogue: C/D layout col = lane&15, row = (lane>>4)*4 + j (verified)
  float bs[4];
#pragma unroll
  for (int n = 0; n < 4; ++n) bs[n] = bias[n0 + n * 16 + l16];

#pragma unroll
  for (int m = 0; m < 4; ++m)
#pragma unroll
    for (int n = 0; n < 4; ++n)
#pragma unroll
      for (int j = 0; j < 4; ++j) {
        int row = m0 + m * 16 + half * 4 + j;
        int col = n0 + n * 16 + l16;
        float v = acc[m][n][j] + bs[n];
        if (OUT_BF16) {
          v = fmaxf(v, 0.0f);
          ((__bf16*)Cv)[(long)row * Ncols + col] = (__bf16)v;
        } else {
          ((float*)Cv)[(long)row * Ncols + col] = v;
        }
      }
}

// ---------------------------------------------------------------------------
// class partial sums, no atomics / no zero-init. grid (64 classes, 8 slices).
// ---------------------------------------------------------------------------
__global__ __launch_bounds__(256) void proto_partial(
    const __bf16* __restrict__ s_emb, const int* __restrict__ labels,
    float* __restrict__ sums_part, int* __restrict__ cnt_part) {
  const int c = blockIdx.x;
  const int s = blockIdx.y;  // 0..7
  const int tid = threadIdx.x;
  const int j0 = s * (N_SUPPORT / 8);
  float a0 = 0.0f, a1 = 0.0f;
  int count = 0;
#pragma unroll 4
  for (int j = j0; j < j0 + N_SUPPORT / 8; j += 4) {
    int4 lab4 = *(const int4*)(labels + j);
#pragma unroll
    for (int u = 0; u < 4; ++u) {
      int lab = (u == 0) ? lab4.x : (u == 1) ? lab4.y : (u == 2) ? lab4.z : lab4.w;
      if (lab == c) {
        const __bf16* r = s_emb + (long)(j + u) * D_EMB;
        a0 += (float)r[tid];
        a1 += (float)r[tid + 256];
        ++count;
      }
    }
  }
  float* dst = sums_part + (long)(c * 8 + s) * D_EMB;
  dst[tid] = a0;
  dst[tid + 256] = a1;
  if (tid == 0) cnt_part[c * 8 + s] = count;
}

// ---------------------------------------------------------------------------
// cpb_part[kc][c][n] = sum_{k in chunk kc} means[c][k] * W1[(D_EMB+k)][n]
// grid (64, 4). b1 folded into qp GEMM bias.
// ---------------------------------------------------------------------------
__global__ __launch_bounds__(256) void proto_cpb(
    const float* __restrict__ sums_part, const int* __restrict__ cnt_part,
    const float* __restrict__ W1, float* __restrict__ cpb_part) {
  __shared__ float ls[128];
  const int c = blockIdx.x;
  const int kc = blockIdx.y;
  const int k0 = kc * 128;
  const int tid = threadIdx.x;

  int nc = 0;
#pragma unroll
  for (int s = 0; s < 8; ++s) nc += cnt_part[c * 8 + s];
  float inv = 1.0f / fmaxf((float)nc, 1.0f);

  if (tid < 128) {
    float v = 0.0f;
#pragma unroll
    for (int s = 0; s < 8; ++s)
      v += sums_part[(long)(c * 8 + s) * D_EMB + k0 + tid];
    ls[tid] = v * inv;
  }
  __syncthreads();

  float acc = 0.0f;
#pragma unroll 8
  for (int k = 0; k < 128; ++k)
    acc = fmaf(ls[k], W1[(long)(D_EMB + k0 + k) * HIDDEN + tid], acc);
  cpb_part[((long)kc * NUM_CLASSES + c) * HIDDEN + tid] = acc;
}

__global__ void cpb_reduce(const float* __restrict__ cpb_part,
                           float* __restrict__ cpb) {
  int i = blockIdx.x * 256 + threadIdx.x;  // 16384 threads
  const int n = NUM_CLASSES * HIDDEN;
  cpb[i] = cpb_part[i] + cpb_part[n + i] + cpb_part[2 * n + i] +
           cpb_part[3 * n + i];
}

// ---------------------------------------------------------------------------
// fused score: out[q][c] = sigmoid( sum_k relu(qp[q,k]+cpb[c,k]) * W2[k] + b2 )
// lane = class c; wave handles 8 q-rows; block = 4 waves = 32 q-rows.
// ---------------------------------------------------------------------------
__global__ __launch_bounds__(256) void score_kernel(
    const float* __restrict__ qp, const float* __restrict__ cpb,
    const float* __restrict__ W2, const float* __restrict__ b2,
    float* __restrict__ out) {
  constexpr int CPB_S = 260;  // f32 stride: 1040 B, 16B aligned
  __shared__ __align__(16) float cpb_s[NUM_CLASSES * CPB_S];
  __shared__ __align__(16) float qp_s[32 * HIDDEN];
  __shared__ __align__(16) float w2_s[HIDDEN];

  const int tid = threadIdx.x;
  const int w = tid >> 6;
  const int c = tid & 63;
  const int qb0 = blockIdx.x * 32;

  w2_s[tid] = W2[tid];
  for (int i = tid; i < NUM_CLASSES * HIDDEN; i += 256)
    cpb_s[(i >> 8) * CPB_S + (i & (HIDDEN - 1))] = cpb[i];
  for (int i = tid; i < 32 * HIDDEN; i += 256)
    qp_s[i] = qp[(long)qb0 * HIDDEN + i];
  __syncthreads();

  const float bb = b2[0];
  float acc[8];
#pragma unroll
  for (int q = 0; q < 8; ++q) acc[q] = 0.0f;

  const float* crow = cpb_s + c * CPB_S;
  const float* qbase = qp_s + (w * 8) * HIDDEN;

#pragma unroll 4
  for (int kc = 0; kc < HIDDEN / 4; ++kc) {
    f32x4 cv = *(const f32x4*)(crow + kc * 4);
    f32x4 wv = *(const f32x4*)(w2_s + kc * 4);
#pragma unroll
    for (int q = 0; q < 8; ++q) {
      f32x4 qv = *(const f32x4*)(qbase + q * HIDDEN + kc * 4);
      acc[q] = fmaf(fmaxf(qv[0] + cv[0], 0.0f), wv[0], acc[q]);
      acc[q] = fmaf(fmaxf(qv[1] + cv[1], 0.0f), wv[1], acc[q]);
      acc[q] = fmaf(fmaxf(qv[2] + cv[2], 0.0f), wv[2], acc[q]);
      acc[q] = fmaf(fmaxf(qv[3] + cv[3], 0.0f), wv[3], acc[q]);
    }
  }

#pragma unroll
  for (int q = 0; q < 8; ++q) {
    float x = acc[q] + bb;
    out[(long)(qb0 + w * 8 + q) * NUM_CLASSES + c] = 1.0f / (1.0f + __expf(-x));
  }
}

// ---------------------------------------------------------------------------
extern "C" void kernel_launch(void* const* d_in, const int* in_sizes, int n_in,
                              void* d_out, int out_size, void* d_ws,
                              size_t ws_size, hipStream_t stream) {
  const float* support = (const float*)d_in[0];
  const float* query   = (const float*)d_in[1];
  const int*   labels  = (const int*)d_in[2];
  const float* W_e     = (const float*)d_in[3];
  const float* b_e     = (const float*)d_in[4];
  const float* W1      = (const float*)d_in[5];
  const float* b1      = (const float*)d_in[6];
  const float* W2      = (const float*)d_in[7];
  const float* b2      = (const float*)d_in[8];
  float* out = (float*)d_out;

  char* ws = (char*)d_ws;
  size_t off = 0;
  auto alloc = [&](size_t bytes) {
    void* p = ws + off;
    off = (off + bytes + 255) & ~(size_t)255;
    return p;
  };
  const long NTOT = N_SUPPORT + N_QUERY;  // 12288
  __bf16* WeT = (__bf16*)alloc((size_t)D_EMB * D_IN * 2);
  __bf16* WqT = (__bf16*)alloc((size_t)HIDDEN * D_EMB * 2);
  __bf16* emb = (__bf16*)alloc((size_t)NTOT * D_EMB * 2);
  float*  qp  = (float*)alloc((size_t)N_QUERY * HIDDEN * 4);
  float*  sums_part = (float*)alloc((size_t)NUM_CLASSES * 8 * D_EMB * 4);
  int*    cnt_part  = (int*)alloc((size_t)NUM_CLASSES * 8 * 4);
  float*  cpb_part  = (float*)alloc((size_t)4 * NUM_CLASSES * HIDDEN * 4);
  float*  cpb       = (float*)alloc((size_t)NUM_CLASSES * HIDDEN * 4);

  // both weight transposes in one dispatch
  transpose_weights<<<640, dim3(32, 8), 0, stream>>>(W_e, W1, WeT, WqT);

  // embeddings: relu([support;query](fp32) @ W_e + b_e) -> bf16 [12288][512]
  // no-LDS 1-wave GEMM, fused fp32->bf16 conversion
  gemm_nolds<D_IN, true, true>
      <<<dim3(NTOT / 64, D_EMB / 64), 64, 0, stream>>>(
          support, query, nullptr, WeT, b_e, emb, D_EMB);

  // class prototypes: partial sums (no atomics) -> projection parts -> reduce
  proto_partial<<<dim3(NUM_CLASSES, 8), 256, 0, stream>>>(emb, labels, sums_part,
                                                          cnt_part);
  proto_cpb<<<dim3(NUM_CLASSES, 4), 256, 0, stream>>>(sums_part, cnt_part, W1,
                                                      cpb_part);
  cpb_reduce<<<NUM_CLASSES * HIDDEN / 256, 256, 0, stream>>>(cpb_part, cpb);

  // qp = q_emb @ Wq + b1  (f32 out [8192][256])
  gemm_nolds<D_EMB, false, false>
      <<<dim3(N_QUERY / 64, HIDDEN / 64), 64, 0, stream>>>(
          nullptr, nullptr, emb + (long)N_SUPPORT * D_EMB, WqT, b1, qp, HIDDEN);

  // fused relation score
  score_kernel<<<N_QUERY / 32, 256, 0, stream>>>(qp, cpb, W2, b2, out);
}

// Round 7
// 97.252 us; speedup vs baseline: 1.4568x; 1.4568x over previous
//
#include <hip/hip_runtime.h>
#include <hip/hip_bf16.h>

// Problem constants
#define D_IN 1024
#define D_EMB 512
#define HIDDEN 256
#define NUM_CLASSES 64
#define N_SUPPORT 4096
#define N_QUERY 8192

typedef __bf16 bf16x8 __attribute__((ext_vector_type(8)));
typedef __bf16 bf16x4 __attribute__((ext_vector_type(4)));
typedef float f32x4 __attribute__((ext_vector_type(4)));

#define GLOAD_LDS16(g, l)                                                          \
  __builtin_amdgcn_global_load_lds(                                                \
      (const __attribute__((address_space(1))) unsigned int*)(g),                  \
      (__attribute__((address_space(3))) unsigned int*)(l), 16, 0, 0)

// ---------------------------------------------------------------------------
// prep: one dispatch does (a) both weight transposes -> bf16 [cols][rows],
// (b) fp32->bf16 convert of [support; query] -> Xbf.
//   blocks [0,512):    W_e [1024][512] -> WeT [512][1024]
//   blocks [512,640):  W1[:512][256]   -> WqT [256][512]
//   blocks [640,3712): convert, 4096 elems per block
// ---------------------------------------------------------------------------
__global__ __launch_bounds__(256) void prep(
    const float* __restrict__ W_e, const float* __restrict__ W1,
    const float* __restrict__ support, const float* __restrict__ query,
    __bf16* __restrict__ WeT, __bf16* __restrict__ WqT,
    __bf16* __restrict__ Xbf) {
  const int tid = threadIdx.x;
  int b = blockIdx.x;
  if (b < 640) {
    __shared__ float tile[32][33];
    const float* in;
    __bf16* out;
    int bx, by, rows, cols;
    if (b < 512) {
      in = W_e; out = WeT; rows = D_IN; cols = D_EMB;
      bx = (b & 15) * 32; by = (b >> 4) * 32;
    } else {
      b -= 512;
      in = W1; out = WqT; rows = D_EMB; cols = HIDDEN;  // W1[:512] only
      bx = (b & 7) * 32; by = (b >> 3) * 32;
    }
    int tx = tid & 31, ty = tid >> 5;
#pragma unroll
    for (int i = ty; i < 32; i += 8)
      tile[i][tx] = in[(long)(by + i) * cols + bx + tx];
    __syncthreads();
#pragma unroll
    for (int i = ty; i < 32; i += 8)
      out[(long)(bx + i) * rows + by + tx] = (__bf16)tile[tx][i];
  } else {
    const long nsup = (long)N_SUPPORT * D_IN;
    long base = (long)(b - 640) * 4096;
#pragma unroll
    for (int g = 0; g < 4; ++g) {
      long i = base + g * 1024 + tid * 4;
      const float* src = (i < nsup) ? (support + i) : (query + (i - nsup));
      float4 v = *(const float4*)src;
      bf16x4 o;
      o[0] = (__bf16)v.x; o[1] = (__bf16)v.y;
      o[2] = (__bf16)v.z; o[3] = (__bf16)v.w;
      *(bf16x4*)(Xbf + i) = o;
    }
  }
}

// ---------------------------------------------------------------------------
// Counted-vmcnt pipelined MFMA GEMM:  C = A[M][K] @ BT[N][K]^T + bias
// BK=32, 4 waves (2x2), 3 LDS buffers, depth-2 prefetch via global_load_lds.
// Raw s_barrier + s_waitcnt vmcnt(LOADS) -- prefetched loads stay in flight
// across the barrier (T3/T4). LDS bank fix: linear dest + inverse-swizzled
// GLOBAL source column + swizzled read slot (rule #21); 8-way -> 2-way.
// ---------------------------------------------------------------------------
template <int BM, int BN, int K, bool OUT_BF16>
__global__ __launch_bounds__(256, 4) void gemm_pipe(
    const __bf16* __restrict__ A, const __bf16* __restrict__ BT,
    const float* __restrict__ bias, void* __restrict__ Cv, int Ncols) {
  constexpr int BK = 32;
  constexpr int NT = K / BK;
  constexpr int MR = BM / 32;      // frags per wave in m (wave rows = BM/2)
  constexpr int NR = BN / 32;      // frags per wave in n
  constexpr int AQ = BM * 4 / 256; // per-thread A 16B-chunks (2 or 1)
  constexpr int LOADS = AQ + 1;    // gload_lds per thread per stage

  __shared__ __align__(16) __bf16 As[3][BM * BK];
  __shared__ __align__(16) __bf16 Bs[3][BN * BK];

  const int tid = threadIdx.x;
  const int wave = tid >> 6, lane = tid & 63;
  const int wr = wave >> 1, wc = wave & 1;
  const int l16 = lane & 15, half = lane >> 4;
  const int slot = half ^ ((l16 >> 1) & 3);  // swizzled 16B slot for reads

  const int m0 = blockIdx.x * BM;
  const int n0 = blockIdx.y * BN;

  f32x4 acc[MR][NR];
#pragma unroll
  for (int m = 0; m < MR; ++m)
#pragma unroll
    for (int n = 0; n < NR; ++n) acc[m][n] = (f32x4)0.0f;

#define STAGE(t, buf)                                                       \
  {                                                                         \
    _Pragma("unroll") for (int q = 0; q < AQ; ++q) {                        \
      int chunk = q * 256 + tid;                                            \
      int row = chunk >> 2;                                                 \
      int kc = (chunk & 3) ^ ((row >> 1) & 3);                              \
      GLOAD_LDS16(A + (long)(m0 + row) * K + (t) * BK + kc * 8,             \
                  &As[buf][chunk * 8]);                                     \
    }                                                                       \
    {                                                                       \
      int chunk = tid;                                                      \
      int row = chunk >> 2;                                                 \
      int kc = (chunk & 3) ^ ((row >> 1) & 3);                              \
      GLOAD_LDS16(BT + (long)(n0 + row) * K + (t) * BK + kc * 8,            \
                  &Bs[buf][chunk * 8]);                                     \
    }                                                                       \
  }

#define COMPUTE(buf)                                                        \
  {                                                                         \
    bf16x8 a[MR], b[NR];                                                    \
    _Pragma("unroll") for (int m = 0; m < MR; ++m)                          \
        a[m] = *(const bf16x8*)(&As[buf][(wr * (BM / 2) + m * 16 + l16) *   \
                                             BK + slot * 8]);               \
    _Pragma("unroll") for (int n = 0; n < NR; ++n)                          \
        b[n] = *(const bf16x8*)(&Bs[buf][(wc * (BN / 2) + n * 16 + l16) *   \
                                             BK + slot * 8]);               \
    asm volatile("s_waitcnt lgkmcnt(0)" ::: "memory");                      \
    __builtin_amdgcn_sched_barrier(0);                                      \
    _Pragma("unroll") for (int m = 0; m < MR; ++m)                          \
        _Pragma("unroll") for (int n = 0; n < NR; ++n)                      \
            acc[m][n] = __builtin_amdgcn_mfma_f32_16x16x32_bf16(            \
                a[m], b[n], acc[m][n], 0, 0, 0);                            \
  }

#define WAIT_PREV()                                                         \
  if constexpr (LOADS == 3) {                                               \
    asm volatile("s_waitcnt vmcnt(3)" ::: "memory");                        \
  } else {                                                                  \
    asm volatile("s_waitcnt vmcnt(2)" ::: "memory");                        \
  }

  // prologue: stage tiles 0,1
  STAGE(0, 0);
  STAGE(1, 1);
  WAIT_PREV();  // tile 0 resident (tile 1's loads still in flight)
  __builtin_amdgcn_s_barrier();

  int cur = 0;
  for (int t = 0; t < NT - 2; ++t) {
    int nb = cur + 2;
    if (nb >= 3) nb -= 3;
    STAGE(t + 2, nb);   // depth-2 prefetch
    COMPUTE(cur);
    WAIT_PREV();        // drain tile t+1's loads; t+2's stay in flight
    __builtin_amdgcn_s_barrier();
    cur = (cur + 1 == 3) ? 0 : cur + 1;
  }
  COMPUTE(cur);  // t = NT-2
  asm volatile("s_waitcnt vmcnt(0)" ::: "memory");
  __builtin_amdgcn_s_barrier();
  cur = (cur + 1 == 3) ? 0 : cur + 1;
  COMPUTE(cur);  // t = NT-1

#undef STAGE
#undef COMPUTE
#undef WAIT_PREV

  // epilogue: C/D layout col = lane&15, row = (lane>>4)*4 + j  [m89/m91]
#pragma unroll
  for (int m = 0; m < MR; ++m)
#pragma unroll
    for (int n = 0; n < NR; ++n) {
      const int col = n0 + wc * (BN / 2) + n * 16 + l16;
      const float bv = bias[col];
#pragma unroll
      for (int j = 0; j < 4; ++j) {
        int row = m0 + wr * (BM / 2) + m * 16 + half * 4 + j;
        float v = acc[m][n][j] + bv;
        if (OUT_BF16) {
          v = fmaxf(v, 0.0f);
          ((__bf16*)Cv)[(long)row * Ncols + col] = (__bf16)v;
        } else {
          ((float*)Cv)[(long)row * Ncols + col] = v;
        }
      }
    }
}

// ---------------------------------------------------------------------------
// class partial sums, no atomics / no zero-init. grid (64 classes, 8 slices).
// ---------------------------------------------------------------------------
__global__ __launch_bounds__(256) void proto_partial(
    const __bf16* __restrict__ s_emb, const int* __restrict__ labels,
    float* __restrict__ sums_part, int* __restrict__ cnt_part) {
  const int c = blockIdx.x;
  const int s = blockIdx.y;  // 0..7
  const int tid = threadIdx.x;
  const int j0 = s * (N_SUPPORT / 8);
  float a0 = 0.0f, a1 = 0.0f;
  int count = 0;
#pragma unroll 4
  for (int j = j0; j < j0 + N_SUPPORT / 8; j += 4) {
    int4 lab4 = *(const int4*)(labels + j);
#pragma unroll
    for (int u = 0; u < 4; ++u) {
      int lab = (u == 0) ? lab4.x : (u == 1) ? lab4.y : (u == 2) ? lab4.z : lab4.w;
      if (lab == c) {
        const __bf16* r = s_emb + (long)(j + u) * D_EMB;
        a0 += (float)r[tid];
        a1 += (float)r[tid + 256];
        ++count;
      }
    }
  }
  float* dst = sums_part + (long)(c * 8 + s) * D_EMB;
  dst[tid] = a0;
  dst[tid + 256] = a1;
  if (tid == 0) cnt_part[c * 8 + s] = count;
}

// ---------------------------------------------------------------------------
// cpb_part[kc][c][n] = sum_{k in chunk kc} means[c][k] * W1[(D_EMB+k)][n]
// grid (64, 4). b1 folded into qp GEMM bias. Summed in score staging.
// ---------------------------------------------------------------------------
__global__ __launch_bounds__(256) void proto_cpb(
    const float* __restrict__ sums_part, const int* __restrict__ cnt_part,
    const float* __restrict__ W1, float* __restrict__ cpb_part) {
  __shared__ float ls[128];
  const int c = blockIdx.x;
  const int kc = blockIdx.y;
  const int k0 = kc * 128;
  const int tid = threadIdx.x;

  int nc = 0;
#pragma unroll
  for (int s = 0; s < 8; ++s) nc += cnt_part[c * 8 + s];
  float inv = 1.0f / fmaxf((float)nc, 1.0f);

  if (tid < 128) {
    float v = 0.0f;
#pragma unroll
    for (int s = 0; s < 8; ++s)
      v += sums_part[(long)(c * 8 + s) * D_EMB + k0 + tid];
    ls[tid] = v * inv;
  }
  __syncthreads();

  float acc = 0.0f;
#pragma unroll 8
  for (int k = 0; k < 128; ++k)
    acc = fmaf(ls[k], W1[(long)(D_EMB + k0 + k) * HIDDEN + tid], acc);
  cpb_part[((long)kc * NUM_CLASSES + c) * HIDDEN + tid] = acc;
}

// ---------------------------------------------------------------------------
// fused score: out[q][c] = sigmoid( sum_k relu(qp[q,k]+cpb[c,k]) * W2[k] + b2 )
// qp already includes b1. cpb_part summed during staging (kills cpb_reduce).
// lane = class c; wave handles 8 q-rows; block = 4 waves = 32 q-rows.
// ---------------------------------------------------------------------------
__global__ __launch_bounds__(256) void score_kernel(
    const float* __restrict__ qp, const float* __restrict__ cpb_part,
    const float* __restrict__ W2, const float* __restrict__ b2,
    float* __restrict__ out) {
  constexpr int CPB_S = 260;  // f32 stride: 1040 B, 16B aligned
  __shared__ __align__(16) float cpb_s[NUM_CLASSES * CPB_S];
  __shared__ __align__(16) float qp_s[32 * HIDDEN];
  __shared__ __align__(16) float w2_s[HIDDEN];

  const int tid = threadIdx.x;
  const int w = tid >> 6;
  const int c = tid & 63;
  const int qb0 = blockIdx.x * 32;
  constexpr int NCH = NUM_CLASSES * HIDDEN;

  w2_s[tid] = W2[tid];
  for (int i = tid; i < NCH; i += 256)
    cpb_s[(i >> 8) * CPB_S + (i & (HIDDEN - 1))] =
        cpb_part[i] + cpb_part[NCH + i] + cpb_part[2 * NCH + i] +
        cpb_part[3 * NCH + i];
  for (int i = tid; i < 32 * HIDDEN; i += 256)
    qp_s[i] = qp[(long)qb0 * HIDDEN + i];
  __syncthreads();

  const float bb = b2[0];
  float acc[8];
#pragma unroll
  for (int q = 0; q < 8; ++q) acc[q] = 0.0f;

  const float* crow = cpb_s + c * CPB_S;
  const float* qbase = qp_s + (w * 8) * HIDDEN;

#pragma unroll 4
  for (int kc = 0; kc < HIDDEN / 4; ++kc) {
    f32x4 cv = *(const f32x4*)(crow + kc * 4);
    f32x4 wv = *(const f32x4*)(w2_s + kc * 4);
#pragma unroll
    for (int q = 0; q < 8; ++q) {
      f32x4 qv = *(const f32x4*)(qbase + q * HIDDEN + kc * 4);
      acc[q] = fmaf(fmaxf(qv[0] + cv[0], 0.0f), wv[0], acc[q]);
      acc[q] = fmaf(fmaxf(qv[1] + cv[1], 0.0f), wv[1], acc[q]);
      acc[q] = fmaf(fmaxf(qv[2] + cv[2], 0.0f), wv[2], acc[q]);
      acc[q] = fmaf(fmaxf(qv[3] + cv[3], 0.0f), wv[3], acc[q]);
    }
  }

#pragma unroll
  for (int q = 0; q < 8; ++q) {
    float x = acc[q] + bb;
    out[(long)(qb0 + w * 8 + q) * NUM_CLASSES + c] = 1.0f / (1.0f + __expf(-x));
  }
}

// ---------------------------------------------------------------------------
extern "C" void kernel_launch(void* const* d_in, const int* in_sizes, int n_in,
                              void* d_out, int out_size, void* d_ws,
                              size_t ws_size, hipStream_t stream) {
  const float* support = (const float*)d_in[0];
  const float* query   = (const float*)d_in[1];
  const int*   labels  = (const int*)d_in[2];
  const float* W_e     = (const float*)d_in[3];
  const float* b_e     = (const float*)d_in[4];
  const float* W1      = (const float*)d_in[5];
  const float* b1      = (const float*)d_in[6];
  const float* W2      = (const float*)d_in[7];
  const float* b2      = (const float*)d_in[8];
  float* out = (float*)d_out;

  char* ws = (char*)d_ws;
  size_t off = 0;
  auto alloc = [&](size_t bytes) {
    void* p = ws + off;
    off = (off + bytes + 255) & ~(size_t)255;
    return p;
  };
  const long NTOT = N_SUPPORT + N_QUERY;  // 12288
  __bf16* Xbf = (__bf16*)alloc((size_t)NTOT * D_IN * 2);            // 25.2 MB
  __bf16* WeT = (__bf16*)alloc((size_t)D_EMB * D_IN * 2);           // 1 MB
  __bf16* WqT = (__bf16*)alloc((size_t)HIDDEN * D_EMB * 2);         // 256 KB
  __bf16* emb = (__bf16*)alloc((size_t)NTOT * D_EMB * 2);           // 12.6 MB
  float*  qp  = (float*)alloc((size_t)N_QUERY * HIDDEN * 4);        // 8.4 MB
  float*  sums_part = (float*)alloc((size_t)NUM_CLASSES * 8 * D_EMB * 4);
  int*    cnt_part  = (int*)alloc((size_t)NUM_CLASSES * 8 * 4);
  float*  cpb_part  = (float*)alloc((size_t)4 * NUM_CLASSES * HIDDEN * 4);

  // transposes + fp32->bf16 convert, one dispatch
  prep<<<640 + (int)(NTOT * D_IN / 4096), 256, 0, stream>>>(
      W_e, W1, support, query, WeT, WqT, Xbf);

  // embeddings: relu(Xbf @ W_e + b_e) -> bf16 [12288][512]
  gemm_pipe<128, 64, D_IN, true>
      <<<dim3(NTOT / 128, D_EMB / 64), 256, 0, stream>>>(
          Xbf, WeT, b_e, emb, D_EMB);

  // class prototypes: partial sums (no atomics) -> projection parts
  proto_partial<<<dim3(NUM_CLASSES, 8), 256, 0, stream>>>(emb, labels, sums_part,
                                                          cnt_part);
  proto_cpb<<<dim3(NUM_CLASSES, 4), 256, 0, stream>>>(sums_part, cnt_part, W1,
                                                      cpb_part);

  // qp = q_emb @ Wq + b1  (f32 out [8192][256])
  gemm_pipe<64, 64, D_EMB, false>
      <<<dim3(N_QUERY / 64, HIDDEN / 64), 256, 0, stream>>>(
          emb + (long)N_SUPPORT * D_EMB, WqT, b1, qp, HIDDEN);

  // fused relation score (cpb_part summed in staging)
  score_kernel<<<N_QUERY / 32, 256, 0, stream>>>(qp, cpb_part, W2, b2, out);
}